// Round 10
// baseline (211.924 us; speedup 1.0000x reference)
//
#include <hip/hip_runtime.h>
#include <hip/hip_fp16.h>
#include <math.h>

#define FDIM  128
#define L1OUT 16
#define L2DIM 17
#define TRM   128     // f-rows per block in node_transform (MFMA version)
#define HSTR  136     // LDS tile row stride in halves (272 B)
#define WSTR  136     // w1t row stride in halves

typedef _Float16 f16x8 __attribute__((ext_vector_type(8)));   // MFMA A/B frag (4 VGPR)
typedef float    f32x4 __attribute__((ext_vector_type(4)));   // MFMA C/D frag

// one 32-byte fp16 node row (16 halves); align 16 -> 2x global_load_dwordx4
struct __align__(16) H16 { __half2 h[8]; };

__device__ __forceinline__ float lrelu(float v) { return v >= 0.f ? v : 0.1f * v; }

// ============================================================================
// K1 (MFMA): [A|B] = f @ W'  where W'[k][c] = W1[k][c] (c<16) / W1[128+k][c-16].
// M=100k, K=128, N=32 -> mfma_f32_16x16x32_f16, 2 N-tiles (nt=0 -> A, 1 -> B).
// R9 lesson: B-frags loaded as 64 scalar global_loads/thread (stride 64B) is
// another TA-grind (R7 class). Now W1 is staged TRANSPOSED into LDS (w1t[n][k],
// fp16) during f-staging; each B-frag is then one ds_read_b128.
// Layouts (HW-verified per guide): A-frag A[m=lane&15][k=(lane>>4)*8+j];
// B-frag B[k=(lane>>4)*8+j][n=lane&15]; C/D col=lane&15, row=(lane>>4)*4+reg.
// + degree atomics folded in (deg zeroed by memsetAsync before this kernel).
// ============================================================================
__global__ void node_transform(
    const float* __restrict__ f, const float* __restrict__ W1,
    const float* __restrict__ b1,
    const int* __restrict__ ind_i, const float* __restrict__ val,
    H16* __restrict__ A, H16* __restrict__ B,
    float* __restrict__ deg, int N, int E)
{
    __shared__ __align__(16) _Float16 tile[TRM * HSTR];   // 34.8 KB
    __shared__ __align__(16) _Float16 w1t[32 * WSTR];     // 8.7 KB (total 43.5 KB)

    const int t    = threadIdx.x;
    const int gtid = blockIdx.x * 256 + t;
    const int GT   = gridDim.x * 256;

    // ---- degree atomics (4 edges/thread, grid-stride, fire-and-forget) ----
    {
        const int E4 = E >> 2;
        for (int q = gtid; q < E4; q += GT) {
            int e = q << 2;
            int4   ii = *reinterpret_cast<const int4*>(ind_i + e);
            float4 vv = *reinterpret_cast<const float4*>(val + e);
            atomicAdd(&deg[ii.x], fabsf(vv.x));
            atomicAdd(&deg[ii.y], fabsf(vv.y));
            atomicAdd(&deg[ii.z], fabsf(vv.z));
            atomicAdd(&deg[ii.w], fabsf(vv.w));
        }
        if (gtid < (E & 3)) {
            int e = (E & ~3) + gtid;
            atomicAdd(&deg[ind_i[e]], fabsf(val[e]));
        }
    }

    // ---- stage W1 transposed into LDS: w1t[n][k] = W1[k + 128*(n>=16)][n&15]
    {
#pragma unroll
        for (int q = 0; q < 4; ++q) {
            int i4 = t + 256 * q;                  // float4 idx over W1 (1024)
            float4 v = reinterpret_cast<const float4*>(W1)[i4];
            int k  = i4 >> 2;                      // W1 row 0..255
            int n0 = (i4 & 3) * 4;                 // col 0,4,8,12
            int nn = (k >= FDIM) ? 16 : 0;         // B-half -> n index 16..31
            int kk = k & (FDIM - 1);
            w1t[(nn + n0 + 0) * WSTR + kk] = (_Float16)v.x;
            w1t[(nn + n0 + 1) * WSTR + kk] = (_Float16)v.y;
            w1t[(nn + n0 + 2) * WSTR + kk] = (_Float16)v.z;
            w1t[(nn + n0 + 3) * WSTR + kk] = (_Float16)v.w;
        }
    }

    // ---- stage 128 f-rows as fp16 into padded LDS tile (coalesced) ----
    const int base = blockIdx.x * TRM;
#pragma unroll
    for (int q = 0; q < 8; ++q) {
        int p  = t + 256 * q;         // half8-chunk index 0..2047
        int r  = p >> 4;              // 16 chunks per row
        int c8 = p & 15;              // chunk within row (8 halves)
        float4 lo = make_float4(0.f, 0.f, 0.f, 0.f);
        float4 hi = lo;
        if (base + r < N) {
            const float4* src = reinterpret_cast<const float4*>(
                f + (size_t)(base + r) * FDIM + c8 * 8);
            lo = src[0];
            hi = src[1];
        }
        f16x8 hx;
        hx[0] = (_Float16)lo.x; hx[1] = (_Float16)lo.y;
        hx[2] = (_Float16)lo.z; hx[3] = (_Float16)lo.w;
        hx[4] = (_Float16)hi.x; hx[5] = (_Float16)hi.y;
        hx[6] = (_Float16)hi.z; hx[7] = (_Float16)hi.w;
        *reinterpret_cast<f16x8*>(&tile[r * HSTR + c8 * 8]) = hx;
    }
    __syncthreads();

    const int lane = t & 63;
    const int wv   = t >> 6;          // wave 0..3
    const int n    = lane & 15;       // MFMA matrix-dim index (col)
    const int quad = lane >> 4;       // k-block / row-group selector

    // ---- B-frags from transposed LDS: one ds_read_b128 each ----
    f16x8 bfr[2][4];
#pragma unroll
    for (int nt = 0; nt < 2; ++nt)
#pragma unroll
        for (int ks = 0; ks < 4; ++ks)
            bfr[nt][ks] = *reinterpret_cast<const f16x8*>(
                &w1t[(nt * 16 + n) * WSTR + 32 * ks + 8 * quad]);
    float b1v = b1[n];                // folded into nt=0 accumulator init

    // ---- compute: wave wv handles M-subtiles wv and wv+4 (16 rows each) ----
#pragma unroll
    for (int si = 0; si < 2; ++si) {
        const int m0 = (wv + 4 * si) * 16;
        f32x4 acc0 = { b1v, b1v, b1v, b1v };      // A-cols + b1
        f32x4 acc1 = { 0.f, 0.f, 0.f, 0.f };      // B-cols
#pragma unroll
        for (int ks = 0; ks < 4; ++ks) {
            // A-frag: row m0+n, k = 32*ks + 8*quad .. +7  (one ds_read_b128)
            f16x8 af = *reinterpret_cast<const f16x8*>(
                &tile[(m0 + n) * HSTR + 32 * ks + 8 * quad]);
            acc0 = __builtin_amdgcn_mfma_f32_16x16x32_f16(af, bfr[0][ks], acc0, 0, 0, 0);
            acc1 = __builtin_amdgcn_mfma_f32_16x16x32_f16(af, bfr[1][ks], acc1, 0, 0, 0);
        }
        // epilogue: D col = n, rows = m0 + quad*4 + reg
#pragma unroll
        for (int reg = 0; reg < 4; ++reg) {
            int node = base + m0 + quad * 4 + reg;
            if (node < N) {
                reinterpret_cast<_Float16*>(A + node)[n] = (_Float16)acc0[reg];
                reinterpret_cast<_Float16*>(B + node)[n] = (_Float16)acc1[reg];
            }
        }
    }
}

// ============================================================================
// K2: per-edge MLP -> exp -> segment-sum. ONE edge per thread — the R3-measured
// clean configuration (64 VGPR, no scratch). 2-edge/thread with LDS weights
// spills ~1.6KB/thread (R5/R6: 658 MB scratch WRITE) — do not revisit without
// SGPR-resident weights. Weights in LDS (stride-20 rows, 16B-aligned).
// Softmax max-pass removed: identical ratios; |e_val| <~ 15 (fp32-safe).
// 256-thread blocks (R10): finer dispatch granularity vs measured 30% occupancy.
// ============================================================================
__global__ void edge_mlp(
    const int* __restrict__ ind, const float* __restrict__ val,
    const H16* __restrict__ A, const H16* __restrict__ B,
    const float* __restrict__ deg,
    const float* __restrict__ W2, const float* __restrict__ b2,
    const float* __restrict__ Wc, const float* __restrict__ bc,
    float* __restrict__ eout, float* __restrict__ ssum, int E)
{
    __shared__ float w2s[L2DIM * 20];   // row c at w2s[c*20], 16B-aligned
    __shared__ float b2s[L2DIM];
    __shared__ float wcs[L2DIM];
    __shared__ float bc0s;

    const int t = threadIdx.x;
    for (int idx = t; idx < L2DIM * L2DIM; idx += 256) {
        int c = idx / L2DIM, r = idx - c * L2DIM;
        w2s[c * 20 + r] = W2[idx];
    }
    if (t < L2DIM) b2s[t] = b2[t];
    if (t < L2DIM) wcs[t] = Wc[t];
    if (t == 0)    bc0s   = bc[0];
    __syncthreads();

    const int e = blockIdx.x * 256 + t;
    if (e >= E) return;

    int   i = ind[e];
    int   j = ind[E + e];
    H16   a  = A[i];                     // 2x global_load_dwordx4 gather
    H16   bb = B[j];
    float v  = val[e];
    float dg = deg[i];

    float x[L2DIM];
#pragma unroll
    for (int q = 0; q < 8; ++q) {
        float2 fa = __half22float2(a.h[q]);
        float2 fb = __half22float2(bb.h[q]);
        x[2 * q]     = lrelu(fa.x + fb.x);       // b1 pre-folded into A
        x[2 * q + 1] = lrelu(fa.y + fb.y);
    }
    x[L1OUT] = fabsf(v) / dg;

    float acc[L2DIM];
#pragma unroll
    for (int r = 0; r < L2DIM; ++r) acc[r] = b2s[r];
#pragma unroll
    for (int c = 0; c < L2DIM; ++c) {
        float xc = x[c];
        const float4* r4 = reinterpret_cast<const float4*>(&w2s[c * 20]);
        float4 w0 = r4[0], w1v = r4[1], w2v = r4[2], w3 = r4[3];
        float  w16 = w2s[c * 20 + 16];
        acc[0]  += xc * w0.x;  acc[1]  += xc * w0.y;
        acc[2]  += xc * w0.z;  acc[3]  += xc * w0.w;
        acc[4]  += xc * w1v.x; acc[5]  += xc * w1v.y;
        acc[6]  += xc * w1v.z; acc[7]  += xc * w1v.w;
        acc[8]  += xc * w2v.x; acc[9]  += xc * w2v.y;
        acc[10] += xc * w2v.z; acc[11] += xc * w2v.w;
        acc[12] += xc * w3.x;  acc[13] += xc * w3.y;
        acc[14] += xc * w3.z;  acc[15] += xc * w3.w;
        acc[16] += xc * w16;
    }
    float ev = bc0s;
#pragma unroll
    for (int r = 0; r < L2DIM; ++r) ev += lrelu(acc[r]) * wcs[r];

    float ex = __expf(ev);
    eout[e] = ex;
    atomicAdd(&ssum[i], ex);
}

// ============================================================================
// K3: out = ex / s[i], 4 edges/thread vectorized
// ============================================================================
__global__ void normalize(const int* __restrict__ ind_i, const float* __restrict__ ssum,
                          float* __restrict__ ex, int E) {
    int t = blockIdx.x * blockDim.x + threadIdx.x;
    int e = t * 4;
    if (e + 3 < E) {
        int4   ii = *reinterpret_cast<const int4*>(ind_i + e);
        float4 vv = *reinterpret_cast<const float4*>(ex + e);
        vv.x /= ssum[ii.x];
        vv.y /= ssum[ii.y];
        vv.z /= ssum[ii.z];
        vv.w /= ssum[ii.w];
        *reinterpret_cast<float4*>(ex + e) = vv;
    } else {
        for (; e < E; ++e) ex[e] = ex[e] / ssum[ind_i[e]];
    }
}

extern "C" void kernel_launch(void* const* d_in, const int* in_sizes, int n_in,
                              void* d_out, int out_size, void* d_ws, size_t ws_size,
                              hipStream_t stream) {
    const int*   Jt_ind = (const int*)  d_in[0];   // [2,E]
    const float* Jt_val = (const float*)d_in[1];   // [E]
    const float* f      = (const float*)d_in[2];   // [N,128]
    const float* W1 = (const float*)d_in[4];       // [256,16]
    const float* b1 = (const float*)d_in[5];       // [16]
    const float* W2 = (const float*)d_in[6];       // [17,17]
    const float* b2 = (const float*)d_in[7];       // [17]
    const float* Wc = (const float*)d_in[8];       // [17,1]
    const float* bc = (const float*)d_in[9];       // [1]

    const int E = in_sizes[1];
    const int N = in_sizes[2] / FDIM;
    float* out = (float*)d_out;                    // [E] fp32

    // workspace: deg[N] | ssum[N] (contiguous -> one memset) | A[N] | B[N]
    char* ws = (char*)d_ws;
    float* deg  = (float*)ws;  ws += (size_t)N * sizeof(float);
    float* ssum = (float*)ws;  ws += (size_t)N * sizeof(float);
    H16*   A    = (H16*)ws;    ws += (size_t)N * sizeof(H16);
    H16*   Bm   = (H16*)ws;    ws += (size_t)N * sizeof(H16);

    const int B256 = 256;
    const int nblk = (N + TRM - 1) / TRM;                   // node tiles (128 rows)
    const int eblk = (E + B256 - 1) / B256;                 // 1 edge/thread
    const int qblk = ((E + 3) / 4 + B256 - 1) / B256;       // 4 edges/thread

    hipMemsetAsync(deg, 0, 2 * (size_t)N * sizeof(float), stream);
    node_transform<<<nblk, B256, 0, stream>>>(f, W1, b1, Jt_ind, Jt_val,
                                              A, Bm, deg, N, E);
    edge_mlp      <<<eblk, B256, 0, stream>>>(Jt_ind, Jt_val, A, Bm, deg,
                                              W2, b2, Wc, bc, out, ssum, E);
    normalize     <<<qblk, B256, 0, stream>>>(Jt_ind, ssum, out, E);
}